// Round 6
// baseline (7548.912 us; speedup 1.0000x reference)
//
#include <hip/hip_runtime.h>

// R6: two-kernel structure.
// 1) xproj_mfma: xp[bt][c] = b_in[c]+b_rec[c]+x[bt]·W_in[c] via 16x16x32 f16
//    MFMA, W_in LDS-staged in B-frag order, all 256 CUs, memory-bound.
// 2) ltc_scan2: 32 WGs x 512 thr (8 waves, 2/SIMD). Wave w: item=w>>2 (2
//    batch items/WG -> stall-filling between barriers), g=w&3 owns 64 cols
//    as 4 tiles. W_rec B-frags stationary (128 regs f16). h state f32 in
//    regs; h exchange via LDS f16, STRIDE-72 permuted layout (R5 lesson:
//    q*64 aliased all q-groups onto bank 0 -> 4-way conflicts; 72 gives
//    banks 4q+4i, conflict-free). acc split into two 4-deep MFMA chains.
//    xp prefetched 2 steps ahead in regs (covers ~900cyc HBM latency).
//    One barrier per layer. Fallback (ws too small): R5 kernel verbatim.

typedef _Float16 half8 __attribute__((ext_vector_type(8)));
typedef _Float16 half4 __attribute__((ext_vector_type(4)));
typedef float    f32x4 __attribute__((ext_vector_type(4)));

__device__ __forceinline__ float fast_tanh(float z) {
    float e = __expf(2.0f * z);        // inf-safe
    return 1.0f - 2.0f / (e + 1.0f);
}

__device__ __forceinline__ half8 cvt8(float4 v0, float4 v1) {
    half8 hv;
    hv[0]=(_Float16)v0.x; hv[1]=(_Float16)v0.y;
    hv[2]=(_Float16)v0.z; hv[3]=(_Float16)v0.w;
    hv[4]=(_Float16)v1.x; hv[5]=(_Float16)v1.y;
    hv[6]=(_Float16)v1.z; hv[7]=(_Float16)v1.w;
    return hv;
}

// permuted h address: k = 32i + 8q + j -> 72q + 8i + j  (stride-72: banks 4q+4i)
__device__ __forceinline__ int hp_addr(int k) {
    return 72 * ((k >> 3) & 3) + 8 * (k >> 5) + (k & 7);
}

// ---------------- prepass: xp = x·W_in^T + b_in + b_rec ----------------
__global__ void __launch_bounds__(256, 2)
xproj_mfma(const float* __restrict__ x, const float* __restrict__ W_in,
           const float* __restrict__ b_in, const float* __restrict__ b_rec,
           float* __restrict__ xp)
{
    __shared__ _Float16 wlds[32768];   // W_in in B-frag order, 64 KB
    const int tid = threadIdx.x, lane = tid & 63, w = tid >> 6;
    const int n = lane & 15, q = lane >> 4;

    {   // stage W_in -> LDS (thread owns col = tid)
        const int col = tid, ct = col >> 4, cn = col & 15;
        const float* wr = W_in + col * 128;
#pragma unroll
        for (int ks = 0; ks < 4; ++ks)
#pragma unroll
            for (int qq = 0; qq < 4; ++qq) {
                float4 v0 = *(const float4*)&wr[32*ks + 8*qq];
                float4 v1 = *(const float4*)&wr[32*ks + 8*qq + 4];
                *(half8*)&wlds[(((ct*4+ks)*4+qq)*16+cn)*8] = cvt8(v0, v1);
            }
    }
    float biasv[16];
#pragma unroll
    for (int ct = 0; ct < 16; ++ct)
        biasv[ct] = b_in[16*ct + n] + b_rec[16*ct + n];
    __syncthreads();

    const int rowbase0 = blockIdx.x * 256 + w * 64;
#pragma unroll 1
    for (int rt = 0; rt < 4; ++rt) {
        const int rb = rowbase0 + rt * 16;
        half8 af[4];
#pragma unroll
        for (int ks = 0; ks < 4; ++ks) {
            const float* xr = x + (size_t)(rb + n) * 128 + 32*ks + 8*q;
            af[ks] = cvt8(*(const float4*)&xr[0], *(const float4*)&xr[4]);
        }
        f32x4 acc[16];
#pragma unroll
        for (int ct = 0; ct < 16; ++ct)
            acc[ct] = (f32x4){biasv[ct], biasv[ct], biasv[ct], biasv[ct]};
#pragma unroll
        for (int ks = 0; ks < 4; ++ks)
#pragma unroll
            for (int ct = 0; ct < 16; ++ct)
                acc[ct] = __builtin_amdgcn_mfma_f32_16x16x32_f16(
                    af[ks], *(const half8*)&wlds[(((ct*4+ks)*4+q)*16+n)*8],
                    acc[ct], 0, 0, 0);
        // D: col = 16ct+n, row = rb + 4q + r
        float* orow = xp + (size_t)(rb + 4*q) * 256 + n;
#pragma unroll
        for (int ct = 0; ct < 16; ++ct)
#pragma unroll
            for (int r = 0; r < 4; ++r)
                orow[(size_t)r * 256 + 16*ct] = acc[ct][r];
    }
}

// ---------------- recurrent scan, 2 items/WG ----------------
__global__ void __launch_bounds__(512, 2) __attribute__((amdgpu_waves_per_eu(2, 2)))
ltc_scan2(const float* __restrict__ xp,     // [B*T, 256]
          const float* __restrict__ W_rec,  // [256,256]
          const float* __restrict__ tau,    // [256]
          const int*   __restrict__ num_layers,
          float*       __restrict__ out,    // [B,256]
          int T, int B)
{
    const int tid  = threadIdx.x;
    const int lane = tid & 63;
    const int w    = tid >> 6;
    const int item = w >> 2;               // 0/1
    const int g    = w & 3;                // col-group: cols [64g, 64g+64)
    const int n    = lane & 15;
    const int q    = lane >> 4;
    const int b    = min(2 * blockIdx.x + item, B - 1);
    const int L    = num_layers[0];

    __shared__ _Float16 hperm[2][2][288];  // [item][buf][stride-72 layout]

    // ---- W_rec B-frags (4 tiles x 8 K-steps), f16, stationary ----
    half8 bh[4][8];
    int   col4[4];
#pragma unroll
    for (int t4 = 0; t4 < 4; ++t4) {
        const int col = 64*g + 16*t4 + n;
        col4[t4] = col;
        const float* rp = &W_rec[col * 256 + 8*q];
#pragma unroll
        for (int i = 0; i < 8; ++i)
            bh[t4][i] = cvt8(*(const float4*)&rp[32*i],
                             *(const float4*)&rp[32*i + 4]);
    }
#pragma unroll
    for (int t4 = 0; t4 < 4; ++t4)
#pragma unroll
        for (int i = 0; i < 8; ++i) asm volatile("" : "+v"(bh[t4][i]));

    float sj[4], hj[4];
    int   haddr[4];
#pragma unroll
    for (int t4 = 0; t4 < 4; ++t4) {
        sj[t4]    = 0.1f / fminf(fmaxf(tau[col4[t4]], 0.1f), 5.0f);
        hj[t4]    = 0.0f;
        haddr[t4] = hp_addr(col4[t4]);
    }

    // zero this item's h buffer 0 (256 threads per item cover 288)
    for (int i = (g * 64 + lane); i < 288; i += 256)
        hperm[item][0][i] = (_Float16)0.0f;

    // ---- xp prefetch pipeline: cur, next in regs; load t+2 each step ----
    const float* xrow = xp + (size_t)b * T * 256;
    float xc[4], xn[4];
#pragma unroll
    for (int t4 = 0; t4 < 4; ++t4) xc[t4] = xrow[col4[t4]];
    {
        const int t1 = (T > 1) ? 1 : 0;
#pragma unroll
        for (int t4 = 0; t4 < 4; ++t4)
            xn[t4] = xrow[(size_t)t1 * 256 + col4[t4]];
    }
    __syncthreads();

    int hb = 0;
    for (int t = 0; t < T; ++t) {
        float xf[4];
        const int tn = (t + 2 < T) ? t + 2 : T - 1;
#pragma unroll
        for (int t4 = 0; t4 < 4; ++t4)
            xf[t4] = xrow[(size_t)tn * 256 + col4[t4]];

        for (int l = 0; l < L; ++l) {
            half8 ah[8];
            const _Float16* hsrc = &hperm[item][hb][0];
#pragma unroll
            for (int i = 0; i < 8; ++i)
                ah[i] = *(const half8*)&hsrc[72*q + 8*i];

            f32x4 a0[4], a1[4];
#pragma unroll
            for (int t4 = 0; t4 < 4; ++t4) {
                a0[t4] = (f32x4){xc[t4], xc[t4], xc[t4], xc[t4]};
                a1[t4] = (f32x4){0.f, 0.f, 0.f, 0.f};
            }
#pragma unroll
            for (int i = 0; i < 4; ++i)
#pragma unroll
                for (int t4 = 0; t4 < 4; ++t4)
                    a0[t4] = __builtin_amdgcn_mfma_f32_16x16x32_f16(
                        ah[i], bh[t4][i], a0[t4], 0, 0, 0);
#pragma unroll
            for (int i = 4; i < 8; ++i)
#pragma unroll
                for (int t4 = 0; t4 < 4; ++t4)
                    a1[t4] = __builtin_amdgcn_mfma_f32_16x16x32_f16(
                        ah[i], bh[t4][i], a1[t4], 0, 0, 0);

            // epilogue: all D rows identical -> component 0; hj stays f32
#pragma unroll
            for (int t4 = 0; t4 < 4; ++t4) {
                float z = a0[t4][0] + a1[t4][0];
                float a = fast_tanh(z);
                hj[t4] += sj[t4] * (a - hj[t4]);
            }
            if (q == 0) {
#pragma unroll
                for (int t4 = 0; t4 < 4; ++t4)
                    hperm[item][hb ^ 1][haddr[t4]] = (_Float16)hj[t4];
            }
            __syncthreads();
            hb ^= 1;
        }
#pragma unroll
        for (int t4 = 0; t4 < 4; ++t4) { xc[t4] = xn[t4]; xn[t4] = xf[t4]; }
    }

    if (q == 0) {
#pragma unroll
        for (int t4 = 0; t4 < 4; ++t4)
            out[(size_t)b * 256 + col4[t4]] = hj[t4];
    }
}

// ---------------- fallback (ws too small): R5 kernel ----------------
__device__ __forceinline__ int hp_addr64(int k) {
    return ((k >> 3) & 3) * 64 + (k >> 5) * 8 + (k & 7);
}
__device__ __forceinline__ int xp_addr32(int k) {
    return ((k >> 3) & 3) * 32 + (k >> 5) * 8 + (k & 7);
}

__global__ void __launch_bounds__(256, 1)
ltc_scan_fb(const float* __restrict__ x, const float* __restrict__ W_in,
            const float* __restrict__ b_in, const float* __restrict__ W_rec,
            const float* __restrict__ b_rec, const float* __restrict__ tau,
            const int* __restrict__ num_layers, float* __restrict__ out, int T)
{
    const int b = blockIdx.x, tid = threadIdx.x;
    const int lane = tid & 63, w = tid >> 6;
    const int n = lane & 15, q = lane >> 4;
    const int L = num_layers[0];

    __shared__ _Float16 hperm[2][256];
    __shared__ _Float16 xperm[2][128];

    half8 bh[4][8];
#pragma unroll
    for (int t4 = 0; t4 < 4; ++t4) {
        const int col = 64*w + 16*t4 + n;
        const float* rp = &W_rec[col * 256 + 8*q];
#pragma unroll
        for (int i = 0; i < 8; ++i)
            bh[t4][i] = cvt8(*(const float4*)&rp[32*i], *(const float4*)&rp[32*i+4]);
    }
    half8 bx[4][4];
#pragma unroll
    for (int t4 = 0; t4 < 4; ++t4) {
        const int col = 64*w + 16*t4 + n;
        const float* rp = &W_in[col * 128 + 8*q];
#pragma unroll
        for (int i = 0; i < 4; ++i)
            bx[t4][i] = cvt8(*(const float4*)&rp[32*i], *(const float4*)&rp[32*i+4]);
    }
    float bias[4], sj[4], hj[4];
    int haddr[4];
#pragma unroll
    for (int t4 = 0; t4 < 4; ++t4) {
        const int col = 64*w + 16*t4 + n;
        bias[t4] = b_in[col] + b_rec[col];
        sj[t4] = 0.1f / fminf(fmaxf(tau[col], 0.1f), 5.0f);
        hj[t4] = 0.0f;
        haddr[t4] = hp_addr64(col);
    }
    if (tid < 256) hperm[0][tid] = (_Float16)0.0f;
    const float* xb = x + (size_t)b * T * 128;
    if (tid < 32) {
        float4 xfv = *(const float4*)&xb[4 * tid];
        half4 hv;
        hv[0]=(_Float16)xfv.x; hv[1]=(_Float16)xfv.y;
        hv[2]=(_Float16)xfv.z; hv[3]=(_Float16)xfv.w;
        *(half4*)&xperm[0][xp_addr32(4 * tid)] = hv;
    }
    __syncthreads();

    int hb = 0;
    for (int t = 0; t < T; ++t) {
        const bool ldx = (tid < 32) && (t + 1 < T);
        float4 xfv;
        if (ldx) xfv = *(const float4*)&xb[(size_t)(t + 1) * 128 + 4 * tid];

        f32x4 px[4];
#pragma unroll
        for (int t4 = 0; t4 < 4; ++t4)
            px[t4] = (f32x4){bias[t4], bias[t4], bias[t4], bias[t4]};
        {
            const _Float16* xsrc = &xperm[t & 1][q * 32];
            half8 ax[4];
#pragma unroll
            for (int i = 0; i < 4; ++i) ax[i] = *(const half8*)&xsrc[8 * i];
#pragma unroll
            for (int i = 0; i < 4; ++i)
#pragma unroll
                for (int t4 = 0; t4 < 4; ++t4)
                    px[t4] = __builtin_amdgcn_mfma_f32_16x16x32_f16(
                        ax[i], bx[t4][i], px[t4], 0, 0, 0);
        }
        for (int l = 0; l < L; ++l) {
            f32x4 acc[4];
#pragma unroll
            for (int t4 = 0; t4 < 4; ++t4) acc[t4] = px[t4];
            const _Float16* hsrc = &hperm[hb][q * 64];
            half8 ah[8];
#pragma unroll
            for (int i = 0; i < 8; ++i) ah[i] = *(const half8*)&hsrc[8 * i];
#pragma unroll
            for (int i = 0; i < 8; ++i)
#pragma unroll
                for (int t4 = 0; t4 < 4; ++t4)
                    acc[t4] = __builtin_amdgcn_mfma_f32_16x16x32_f16(
                        ah[i], bh[t4][i], acc[t4], 0, 0, 0);
#pragma unroll
            for (int t4 = 0; t4 < 4; ++t4) {
                float z = acc[t4][0];
                float a = fast_tanh(z);
                hj[t4] += sj[t4] * (a - hj[t4]);
            }
            if (q == 0) {
#pragma unroll
                for (int t4 = 0; t4 < 4; ++t4)
                    hperm[hb ^ 1][haddr[t4]] = (_Float16)hj[t4];
            }
            if (l == L - 1 && ldx) {
                half4 hv;
                hv[0]=(_Float16)xfv.x; hv[1]=(_Float16)xfv.y;
                hv[2]=(_Float16)xfv.z; hv[3]=(_Float16)xfv.w;
                *(half4*)&xperm[(t + 1) & 1][xp_addr32(4 * tid)] = hv;
            }
            __syncthreads();
            hb ^= 1;
        }
    }
    if (q == 0) {
#pragma unroll
        for (int t4 = 0; t4 < 4; ++t4)
            out[(size_t)b * 256 + 64*w + 16*t4 + n] = hj[t4];
    }
}

extern "C" void kernel_launch(void* const* d_in, const int* in_sizes, int n_in,
                              void* d_out, int out_size, void* d_ws, size_t ws_size,
                              hipStream_t stream) {
    const float* x     = (const float*)d_in[0];
    const float* W_in  = (const float*)d_in[1];
    const float* b_in  = (const float*)d_in[2];
    const float* W_rec = (const float*)d_in[3];
    const float* b_rec = (const float*)d_in[4];
    const float* tau   = (const float*)d_in[5];
    const int*   numl  = (const int*)d_in[6];

    const int H = in_sizes[2];            // 256
    const int I = in_sizes[1] / H;        // 128
    const int B = out_size / H;           // 64
    const int T = in_sizes[0] / (B * I);  // 4096
    const size_t xp_bytes = (size_t)B * T * H * sizeof(float);

    if (ws_size >= xp_bytes && ((B * T) % 256) == 0) {
        float* xp = (float*)d_ws;
        xproj_mfma<<<(B * T) / 256, 256, 0, stream>>>(x, W_in, b_in, b_rec, xp);
        ltc_scan2<<<(B + 1) / 2, 512, 0, stream>>>(xp, W_rec, tau, numl,
                                                   (float*)d_out, T, B);
    } else {
        ltc_scan_fb<<<B, 256, 0, stream>>>(x, W_in, b_in, W_rec, b_rec, tau,
                                           numl, (float*)d_out, T);
    }
}